// Round 6
// baseline (168.227 us; speedup 1.0000x reference)
//
#include <hip/hip_runtime.h>
#include <hip/hip_bf16.h>

// GlassBlur via permutation composition.
// final_plane(p) = plane(P(p)),  P = tau_1 o tau_2 o ... o tau_N (first swap leftmost),
// so for chunks A (earlier) and B (later):  P(p) = A(B(p)).
// leaf32: deltas pre-packed to 4-bit window indices in LDS (serial chain touches
// NO global memory), per-row perms built in a 3x3 register window, in-block tree
// -> span-32 nodes. Then compose128 -> final root P -> apply -> blur2.
#define KW0 0.91921792f
#define KW1 0.04038762f
#define KW2 3.42560e-6f

#define HH 224
#define WW 224
#define NSW 49729          // 223*223
#define IMG_STRIDE 62720   // u16 entries per image per perm buffer
#define SLOT32 7616        // 34 rows x 224
#define N128_ENT 28896     // 129 rows x 224 (span-128 node, rows 95..223)
#define N95_OFF 28896      // span-95 node offset (rows 0..96)

// support rows for chunk covering swap-rows u in [u0, u0+nu)
__device__ __forceinline__ void node_meta(int u0, int nu, int& ys, int& nr) {
    ys = max(0, 223 - u0 - nu);
    int ye = min(223, 224 - u0);
    nr = ye - ys + 1;
}

// ---------------- blur1: f32 -> quantize u8 -> blur -> u8 plane ----------------
__global__ __launch_bounds__(256) void blur1_kernel(const float* __restrict__ x,
                                                    unsigned char* __restrict__ img) {
    const int rb = blockIdx.x, c = blockIdx.y, b = blockIdx.z;
    const int y0 = rb * 8;
    __shared__ float A[12][WW];
    __shared__ float Bv[8][WW];
    const float* xp = x + ((size_t)(b * 3 + c)) * HH * WW;

    for (int l = threadIdx.x; l < 12 * WW; l += 256) {
        int r = l / WW, xx = l - r * WW;
        int gy = min(max(y0 + r - 2, 0), HH - 1);
        float v = xp[gy * WW + xx];
        v = floorf(fminf(fmaxf(v * 255.0f, 0.0f), 255.0f));
        A[r][xx] = v;
    }
    __syncthreads();
    for (int l = threadIdx.x; l < 8 * WW; l += 256) {
        int r = l / WW, xx = l - r * WW;
        Bv[r][xx] = KW2 * A[r][xx] + KW1 * A[r + 1][xx] + KW0 * A[r + 2][xx]
                  + KW1 * A[r + 3][xx] + KW2 * A[r + 4][xx];
    }
    __syncthreads();
    unsigned char* op = img + ((size_t)(b * 3 + c)) * HH * WW;
    for (int l = threadIdx.x; l < 8 * WW; l += 256) {
        int r = l / WW, xx = l - r * WW;
        int c0 = max(xx - 2, 0), c1 = max(xx - 1, 0);
        int c3 = min(xx + 1, WW - 1), c4 = min(xx + 2, WW - 1);
        float s = KW2 * Bv[r][c0] + KW1 * Bv[r][c1] + KW0 * Bv[r][xx]
                + KW1 * Bv[r][c3] + KW2 * Bv[r][c4];
        op[(y0 + r) * WW + xx] = (unsigned char)floorf(s);
    }
}

// ---------------- leaf32: packed-idx register-window build + tree to span-32 ----------
// grid (7, 64) = (node j: rows u in [32j,32j+32), image b), 256 threads.
// Phase 0: pack idx = clamp(dy)*3 + clamp(dx) as 4-bit nibbles into LDS (parallel).
// Phase 1: lane l (<32) builds row u=32j+l; 3x3 register window; col x+1 retires via
//          ONE ds_write_b64 per step into col-major leaf [225 cols][4 u16]. No global.
// Phase 2/3: chase 8 leaves -> span-8 nodes; chase 4 nodes -> span-32, write global.
__global__ __launch_bounds__(256) void leaf32_kernel(const int* __restrict__ deltas,
                                                     unsigned short* __restrict__ outB) {
    const int j = blockIdx.x;
    const int b = blockIdx.y;
    const int u0blk = j * 32;
    const int uEnd = min(u0blk + 32, 223);
    const int nuT = uEnd - u0blk;

    __shared__ __align__(16) unsigned short leafS[32 * 900];  // 57600 B: 32 x [225][4]
    __shared__ unsigned short auxS[4 * 2240];                 // 17920 B
    __shared__ unsigned pk[32 * 29];                          //  3712 B (stride 29)

    const int tid = threadIdx.x;
    const int u = u0blk + tid;

    // ---- Phase 0: pack window indices (4 bits/swap, 8 per u32) ----
    {
        const int2* Dbase = (const int2*)deltas + (size_t)b * NSW + (size_t)u0blk * 223;
        for (int w = tid; w < 32 * 28; w += 256) {
            const int r = w / 28, k = w - r * 28;
            if (u0blk + r < 223) {
                const int base = r * 223 + 8 * k;
                unsigned word = 0;
#pragma unroll
                for (int jj = 0; jj < 8; ++jj) {
                    const int i = 8 * k + jj;
                    unsigned idx = 4u;                       // no-op pad
                    if (i < 223) {
                        int2 d = Dbase[base + jj];
                        unsigned px = (unsigned)d.x, py = (unsigned)d.y;
                        if (u0blk + r == 0) px = min(px, 1u);   // y=223 row clamp
                        if (i == 0) py = min(py, 1u);           // x=223 col clamp
                        idx = px * 3u + py;
                    }
                    word |= idx << (4 * jj);
                }
                pk[r * 29 + k] = word;
            }
        }
    }
    __syncthreads();

    // ---- Phase 1: serial build, LDS/VALU only ----
    if (tid < 32 && u < 223) {
        const int y = 223 - u;
        const int b0r = (y - 1) * 224, b1r = y * 224, b2r = (y + 1) * 224;
        uint2* Lf2 = ((uint2*)leafS) + tid * 225;
        const unsigned* pkr = &pk[tid * 29];

        // window w{row}{role}: init for x=223 -> roles (0,1,2) = cols (222,223,224junk)
        unsigned w00 = b0r + 222, w01 = b0r + 223, w02 = b0r + 224;
        unsigned w10 = b1r + 222, w11 = b1r + 223, w12 = b1r + 224;
        unsigned w20 = b2r + 222, w21 = b2r + 223, w22 = b2r + 224;

        unsigned wA_ = pkr[0], wB_ = pkr[1], wC_ = pkr[2];

#define GB_STEP(KK, CA, CB, CC) {                                               \
            const int x_ = 223 - (ibase + (KK));                                \
            const unsigned wsel_ = (((KK) >> 3) == 0) ? wA_                     \
                                 : ((((KK) >> 3) == 1) ? wB_ : wC_);            \
            const unsigned idx_ = (wsel_ >> (4 * ((KK) & 7))) & 15u;            \
            unsigned v_ = w0##CA;                                               \
            v_ = idx_ == 1 ? w0##CB : v_;  v_ = idx_ == 2 ? w0##CC : v_;        \
            v_ = idx_ == 3 ? w1##CA : v_;  v_ = idx_ == 4 ? w1##CB : v_;        \
            v_ = idx_ == 5 ? w1##CC : v_;  v_ = idx_ == 6 ? w2##CA : v_;        \
            v_ = idx_ == 7 ? w2##CB : v_;  v_ = idx_ == 8 ? w2##CC : v_;        \
            const unsigned c_ = w1##CB;                                         \
            w0##CA = idx_ == 0 ? c_ : w0##CA;                                   \
            w0##CB = idx_ == 1 ? c_ : w0##CB;                                   \
            w0##CC = idx_ == 2 ? c_ : w0##CC;                                   \
            w1##CA = idx_ == 3 ? c_ : w1##CA;                                   \
            w1##CC = idx_ == 5 ? c_ : w1##CC;                                   \
            w2##CA = idx_ == 6 ? c_ : w2##CA;                                   \
            w2##CB = idx_ == 7 ? c_ : w2##CB;                                   \
            w2##CC = idx_ == 8 ? c_ : w2##CC;                                   \
            w1##CB = v_;                                                        \
            Lf2[x_ + 1] = make_uint2((w0##CC & 0xffffu) | (w1##CC << 16), w2##CC); \
            w0##CC = (unsigned)(b0r + (x_ - 2));                                \
            w1##CC = (unsigned)(b1r + (x_ - 2));                                \
            w2##CC = (unsigned)(b2r + (x_ - 2));                                \
        }
#define GB_TRIPLE(K0) GB_STEP((K0), 0, 1, 2) GB_STEP((K0)+1, 2, 0, 1) GB_STEP((K0)+2, 1, 2, 0)

        for (int blk = 0; blk < 9; ++blk) {           // i = 0..215
            const int ibase = 24 * blk;
            const unsigned nA_ = pkr[min(3 * blk + 3, 27)];
            const unsigned nB_ = pkr[min(3 * blk + 4, 27)];
            const unsigned nC_ = pkr[min(3 * blk + 5, 27)];
            GB_TRIPLE(0)  GB_TRIPLE(3)  GB_TRIPLE(6)  GB_TRIPLE(9)
            GB_TRIPLE(12) GB_TRIPLE(15) GB_TRIPLE(18) GB_TRIPLE(21)
            wA_ = nA_; wB_ = nB_; wC_ = nC_;
        }
        {                                             // i = 216..222
            const int ibase = 216;
            GB_TRIPLE(0) GB_TRIPLE(3) GB_STEP(6, 0, 1, 2)
        }
        // final emit: col 1 (role 1), col 0 (role 0)
        Lf2[1] = make_uint2((w01 & 0xffffu) | (w11 << 16), w21);
        Lf2[0] = make_uint2((w00 & 0xffffu) | (w10 << 16), w20);
#undef GB_TRIPLE
#undef GB_STEP
    }
    __syncthreads();

    // ---- Phase 2: chase 8 leaves (latest->earliest) -> span-8 node in auxS ----
    for (int k = 0; k < 4; ++k) {
        const int u0 = u0blk + 8 * k;
        const int nu = min(8, uEnd - u0);
        int ysO, nrO; node_meta(u0, nu, ysO, nrO);
        unsigned short* R = &auxS[k * 2240];
        const int cnt = nrO * 224;
        for (int e = tid; e < cnt; e += 512) {
            const int e2 = e + 256;
            const bool has2 = e2 < cnt;
            const int pr1 = ysO + e / 224, pc1 = e % 224;
            unsigned q1 = (unsigned)(pr1 * 224 + pc1);
            const int pr2 = ysO + e2 / 224, pc2 = e2 % 224;
            unsigned q2 = (unsigned)(pr2 * 224 + pc2);
            for (int m = nu - 1; m >= 0; --m) {
                const int lbase = (8 * k + m) * 900;
                const int ys = 222 - (u0 + m);
                { const int qr = (int)(q1 / 224u), qc = (int)q1 - qr * 224, off = qr - ys;
                  if (off >= 0 && off < 3) q1 = leafS[lbase + qc * 4 + off]; }
                { const int qr = (int)(q2 / 224u), qc = (int)q2 - qr * 224, off = qr - ys;
                  if (off >= 0 && off < 3) q2 = leafS[lbase + qc * 4 + off]; }
            }
            R[e] = (unsigned short)q1;
            if (has2) R[e2] = (unsigned short)q2;
        }
    }
    __syncthreads();

    // ---- Phase 3: chase 4 span-8 nodes -> span-32 node, write global ----
    {
        int ysO, nrO; node_meta(u0blk, nuT, ysO, nrO);
        unsigned short* R = outB + (size_t)b * IMG_STRIDE + (size_t)j * SLOT32;
        int ysA[4], nrA[4];
#pragma unroll
        for (int m = 0; m < 4; ++m) {
            const int u0 = u0blk + 8 * m;
            const int nu = min(8, uEnd - u0);
            node_meta(u0, nu, ysA[m], nrA[m]);
        }
        const int cnt = nrO * 224;
        for (int e = tid; e < cnt; e += 512) {
            const int e2 = e + 256;
            const bool has2 = e2 < cnt;
            const int pr1 = ysO + e / 224, pc1 = e % 224;
            unsigned q1 = (unsigned)(pr1 * 224 + pc1);
            const int pr2 = ysO + e2 / 224, pc2 = e2 % 224;
            unsigned q2 = (unsigned)(pr2 * 224 + pc2);
#pragma unroll
            for (int m = 3; m >= 0; --m) {
                { const int qr = (int)(q1 / 224u), qc = (int)q1 - qr * 224, off = qr - ysA[m];
                  if (off >= 0 && off < nrA[m]) q1 = auxS[m * 2240 + off * 224 + qc]; }
                { const int qr = (int)(q2 / 224u), qc = (int)q2 - qr * 224, off = qr - ysA[m];
                  if (off >= 0 && off < nrA[m]) q2 = auxS[m * 2240 + off * 224 + qc]; }
            }
            R[e] = (unsigned short)q1;
            if (has2) R[e2] = (unsigned short)q2;
        }
    }
}

// ---------------- C2: compose span-32 nodes -> span-128 (jo=0) / span-95 (jo=1) --------
__global__ __launch_bounds__(256) void compose128_kernel(const unsigned short* __restrict__ in,
                                                         unsigned short* __restrict__ out) {
    const int b = blockIdx.x, jo = blockIdx.y, sp = blockIdx.z;
    const int nStage = jo == 0 ? 3 : 2;
    const int jD = jo == 0 ? 3 : 6;
    const int u0 = jo * 128;
    const int nu = min(128, 223 - u0);
    int ysO, nrO; node_meta(u0, nu, ysO, nrO);
    __shared__ unsigned short sm[3][SLOT32];   // 45.7 KB
    int ysS[3], nrS[3];
    const unsigned short* base = in + (size_t)b * IMG_STRIDE;
#pragma unroll
    for (int m = 0; m < 3; ++m) {
        ysS[m] = 0; nrS[m] = 0;
        if (m < nStage) {
            int ju = 4 * jo + m;
            int nuu = min(32, 223 - 32 * ju);
            node_meta(32 * ju, nuu, ysS[m], nrS[m]);
            for (int l = threadIdx.x; l < nrS[m] * 224; l += 256)
                sm[m][l] = base[ju * SLOT32 + l];
        }
    }
    int ysD, nrD;
    {
        int nuu = min(32, 223 - 32 * jD);
        node_meta(32 * jD, nuu, ysD, nrD);
    }
    const unsigned short* D = base + (size_t)jD * SLOT32;
    __syncthreads();
    unsigned short* R = out + (size_t)b * IMG_STRIDE + (jo ? N95_OFF : 0);
    const int cnt = nrO * 224;
    const int chunk = (cnt + 3) / 4;
    const int e0 = sp * chunk, e1 = min(cnt, e0 + chunk);
    for (int e = e0 + threadIdx.x; e < e1; e += 256) {
        int pr = ysO + e / 224, pc = e % 224;
        unsigned q = pr * 224 + pc;
        int dr = pr - ysD;
        if (dr >= 0 && dr < nrD) q = D[dr * 224 + pc];
#pragma unroll
        for (int m = 2; m >= 0; --m) {
            if (m < nStage) {
                int qr = q / 224u, qc = q % 224u;
                int rr = qr - ysS[m];
                if (rr >= 0 && rr < nrS[m]) q = sm[m][rr * 224 + qc];
            }
        }
        R[e] = (unsigned short)q;
    }
}

// ---------------- C3: root P = A(span-128, rows 95..223) o B(span-95, rows 0..96) ------
__global__ __launch_bounds__(256) void compose_final_kernel(const unsigned short* __restrict__ in,
                                                            unsigned short* __restrict__ out) {
    const int b = blockIdx.x, sp = blockIdx.y;
    __shared__ unsigned short A[N128_ENT];     // 57792 B
    const unsigned short* base = in + (size_t)b * IMG_STRIDE;
    for (int l = threadIdx.x; l < N128_ENT / 8; l += 256)
        ((uint4*)A)[l] = ((const uint4*)base)[l];
    const unsigned short* Bn = base + N95_OFF;
    __syncthreads();
    unsigned short* R = out + (size_t)b * IMG_STRIDE;
    const int e0 = sp * 12544;
    for (int e = e0 + threadIdx.x; e < e0 + 12544; e += 256) {
        int pr = e / 224;
        unsigned q = (unsigned)e;
        if (pr < 97) q = Bn[e];
        unsigned qr = q / 224u;
        if (qr >= 95) q = A[q - 95 * 224];
        R[e] = (unsigned short)q;
    }
}

// ---------------- apply: plane(p) <- plane(P(p)), in-place via LDS ----------------
__global__ __launch_bounds__(256) void apply_kernel(unsigned char* __restrict__ img,
                                                    const unsigned short* __restrict__ P) {
    const int plane = blockIdx.x;
    const int b = plane / 3;
    __shared__ __align__(16) unsigned char im[HH * WW];
    unsigned char* g = img + (size_t)plane * (HH * WW);
    for (int l = threadIdx.x; l < (HH * WW) / 16; l += 256)
        ((int4*)im)[l] = ((const int4*)g)[l];
    __syncthreads();
    const unsigned short* Pp = P + (size_t)b * IMG_STRIDE;
    for (int t = threadIdx.x; t < (HH * WW) / 8; t += 256) {
        uint4 pe = ((const uint4*)Pp)[t];
        unsigned e0 = pe.x & 0xffffu, e1 = pe.x >> 16;
        unsigned e2 = pe.y & 0xffffu, e3 = pe.y >> 16;
        unsigned e4 = pe.z & 0xffffu, e5 = pe.z >> 16;
        unsigned e6 = pe.w & 0xffffu, e7 = pe.w >> 16;
        unsigned lo = (unsigned)im[e0] | ((unsigned)im[e1] << 8)
                    | ((unsigned)im[e2] << 16) | ((unsigned)im[e3] << 24);
        unsigned hi = (unsigned)im[e4] | ((unsigned)im[e5] << 8)
                    | ((unsigned)im[e6] << 16) | ((unsigned)im[e7] << 24);
        ((uint2*)g)[t] = make_uint2(lo, hi);
    }
}

// ---------------- blur2: u8 plane -> blur -> floor/clip -> f32 /255 ----------------
__global__ __launch_bounds__(256) void blur2_kernel(const unsigned char* __restrict__ img,
                                                    float* __restrict__ out) {
    const int rb = blockIdx.x, c = blockIdx.y, b = blockIdx.z;
    const int y0 = rb * 8;
    __shared__ float A[12][WW];
    __shared__ float Bv[8][WW];
    const unsigned char* ip = img + ((size_t)(b * 3 + c)) * HH * WW;

    for (int l = threadIdx.x; l < 12 * WW; l += 256) {
        int r = l / WW, xx = l - r * WW;
        int gy = min(max(y0 + r - 2, 0), HH - 1);
        A[r][xx] = (float)ip[gy * WW + xx];
    }
    __syncthreads();
    for (int l = threadIdx.x; l < 8 * WW; l += 256) {
        int r = l / WW, xx = l - r * WW;
        Bv[r][xx] = KW2 * A[r][xx] + KW1 * A[r + 1][xx] + KW0 * A[r + 2][xx]
                  + KW1 * A[r + 3][xx] + KW2 * A[r + 4][xx];
    }
    __syncthreads();
    float* op = out + ((size_t)(b * 3 + c)) * HH * WW;
    for (int l = threadIdx.x; l < 8 * WW; l += 256) {
        int r = l / WW, xx = l - r * WW;
        int c0 = max(xx - 2, 0), c1 = max(xx - 1, 0);
        int c3 = min(xx + 1, WW - 1), c4 = min(xx + 2, WW - 1);
        float s = KW2 * Bv[r][c0] + KW1 * Bv[r][c1] + KW0 * Bv[r][xx]
                + KW1 * Bv[r][c3] + KW2 * Bv[r][c4];
        s = fminf(fmaxf(s, 0.0f), 255.0f);
        op[(y0 + r) * WW + xx] = floorf(s) / 255.0f;
    }
}

extern "C" void kernel_launch(void* const* d_in, const int* in_sizes, int n_in,
                              void* d_out, int out_size, void* d_ws, size_t ws_size,
                              hipStream_t stream) {
    const float* x      = (const float*)d_in[0];
    const int*   deltas = (const int*)d_in[1];
    float*       out    = (float*)d_out;
    unsigned char* img  = (unsigned char*)d_ws;                 // 9,633,792 B

    unsigned short* bufA = (unsigned short*)d_out;              // 8.03 MB
    unsigned short* bufB = bufA + (size_t)64 * IMG_STRIDE;      // 8.03 MB

    dim3 gb(28, 3, 64);
    blur1_kernel<<<gb, 256, 0, stream>>>(x, img);

    leaf32_kernel<<<dim3(7, 64), 256, 0, stream>>>(deltas, bufB);         // span-32 -> bufB
    compose128_kernel<<<dim3(64, 2, 4), 256, 0, stream>>>(bufB, bufA);    // 128/95 -> bufA
    compose_final_kernel<<<dim3(64, 4), 256, 0, stream>>>(bufA, bufB);    // root P -> bufB

    apply_kernel<<<dim3(192), 256, 0, stream>>>(img, bufB);
    blur2_kernel<<<gb, 256, 0, stream>>>(img, out);
}

// Round 7
// 143.615 us; speedup vs baseline: 1.1714x; 1.1714x over previous
//
#include <hip/hip_runtime.h>
#include <hip/hip_bf16.h>

// GlassBlur via permutation composition.
// final_plane(p) = plane(P(p)),  P = tau_1 o tau_2 o ... o tau_N (first swap leftmost),
// so for chunks A (earlier, lower u) and B (later):  P(p) = A(B(p)).
// leaf32: pack deltas to 4-bit idx in LDS -> register-window row perms ->
// BINARY in-block tree (2-hop branch-free levels) -> span-32 nodes.
// compose_root: stage all 7 span-32 nodes in LDS, 7 clamped hops/entry -> root P.
// apply -> blur2.
#define KW0 0.91921792f
#define KW1 0.04038762f
#define KW2 3.42560e-6f

#define HH 224
#define WW 224
#define NSW 49729          // 223*223
#define IMG_STRIDE 62720   // u16 entries per image per perm buffer
#define SLOT32 7616        // 34 rows x 224

// support rows for chunk covering swap-rows u in [u0, u0+nu)
__device__ __forceinline__ void node_meta(int u0, int nu, int& ys, int& nr) {
    ys = max(0, 223 - u0 - nu);
    int ye = min(223, 224 - u0);
    nr = ye - ys + 1;
}

// ---------------- blur1: f32 -> quantize u8 -> blur -> u8 plane ----------------
__global__ __launch_bounds__(256) void blur1_kernel(const float* __restrict__ x,
                                                    unsigned char* __restrict__ img) {
    const int rb = blockIdx.x, c = blockIdx.y, b = blockIdx.z;
    const int y0 = rb * 8;
    __shared__ float A[12][WW];
    __shared__ float Bv[8][WW];
    const float* xp = x + ((size_t)(b * 3 + c)) * HH * WW;

    for (int l = threadIdx.x; l < 12 * WW; l += 256) {
        int r = l / WW, xx = l - r * WW;
        int gy = min(max(y0 + r - 2, 0), HH - 1);
        float v = xp[gy * WW + xx];
        v = floorf(fminf(fmaxf(v * 255.0f, 0.0f), 255.0f));
        A[r][xx] = v;
    }
    __syncthreads();
    for (int l = threadIdx.x; l < 8 * WW; l += 256) {
        int r = l / WW, xx = l - r * WW;
        Bv[r][xx] = KW2 * A[r][xx] + KW1 * A[r + 1][xx] + KW0 * A[r + 2][xx]
                  + KW1 * A[r + 3][xx] + KW2 * A[r + 4][xx];
    }
    __syncthreads();
    unsigned char* op = img + ((size_t)(b * 3 + c)) * HH * WW;
    for (int l = threadIdx.x; l < 8 * WW; l += 256) {
        int r = l / WW, xx = l - r * WW;
        int c0 = max(xx - 2, 0), c1 = max(xx - 1, 0);
        int c3 = min(xx + 1, WW - 1), c4 = min(xx + 2, WW - 1);
        float s = KW2 * Bv[r][c0] + KW1 * Bv[r][c1] + KW0 * Bv[r][xx]
                + KW1 * Bv[r][c3] + KW2 * Bv[r][c4];
        op[(y0 + r) * WW + xx] = (unsigned char)floorf(s);
    }
}

// ---- branch-free binary-tree level: out node jo = child[2jo] o child[2jo+1] ----
// child nodes row-major [nr][224] at stride CSLOT, allocated rows = CCAP+1.
template<int NOUT, int CSPAN, int CSLOT, int CCAP, int OSLOT>
__device__ __forceinline__ void level_ds(const unsigned short* __restrict__ child,
                                         unsigned short* __restrict__ outp,
                                         int U, int uEnd, int tid) {
    if (tid >= 224) return;
    for (int jo = 0; jo < NOUT; ++jo) {
        const int u0 = U + jo * (2 * CSPAN);
        const int nu = min(2 * CSPAN, uEnd - u0);        // >= 1 for existing nodes
        int ysO, nrO; node_meta(u0, nu, ysO, nrO);
        const int nuA = min(CSPAN, uEnd - u0);
        int ysA, nrA; node_meta(u0, nuA, ysA, nrA);
        const int nuB = min(CSPAN, uEnd - (u0 + CSPAN));
        int ysB = 0, nrB = 0;
        if (nuB > 0) node_meta(u0 + CSPAN, nuB, ysB, nrB);
        const unsigned short* Ap = child + (2 * jo) * CSLOT;
        const unsigned short* Bp = child + (2 * jo + 1) * CSLOT;
        unsigned short* R = outp + jo * OSLOT;
#pragma unroll 2
        for (int row = 0; row < nrO; ++row) {
            const int pr = ysO + row;
            unsigned q = (unsigned)(pr * 224 + tid);
            {   // B hop (row known, coalesced)
                const int off = pr - ysB;
                const int offc = min(max(off, 0), CCAP);
                const unsigned r = Bp[offc * 224 + tid];
                q = ((unsigned)off < (unsigned)nrB) ? r : q;
            }
            {   // A hop (gather)
                const unsigned qr = q / 224u;
                const int qc = (int)(q - qr * 224u);
                const int off = (int)qr - ysA;
                const int offc = min(max(off, 0), CCAP);
                const unsigned r = Ap[offc * 224 + qc];
                q = ((unsigned)off < (unsigned)nrA) ? r : q;
            }
            R[row * 224 + tid] = (unsigned short)q;
        }
    }
}

// ---------------- leaf32: pack -> register-window build -> binary tree -> span-32 -----
// grid (7, 64) = (node j: rows u in [32j,32j+32), image b), 256 threads.
__global__ __launch_bounds__(256) void leaf32_kernel(const int* __restrict__ deltas,
                                                     unsigned short* __restrict__ outB) {
    const int j = blockIdx.x;
    const int b = blockIdx.y;
    const int U = j * 32;
    const int uEnd = min(U + 32, 223);

    __shared__ unsigned short smA[21632];   // leaves (32x676) / L2 (8x1348) / L4 (2x4036)
    __shared__ unsigned short smB[14400];   // L1 (16x900) / L3 (4x2244)
    __shared__ unsigned pk[32 * 29];        // packed window indices

    const int tid = threadIdx.x;
    const int u = U + tid;

    // ---- Phase 0: pack idx = clamp(dy)*3 + clamp(dx), 8 nibbles per u32 ----
    {
        const int2* Dbase = (const int2*)deltas + (size_t)b * NSW + (size_t)U * 223;
        for (int w = tid; w < 32 * 28; w += 256) {
            const int r = w / 28, k = w - r * 28;
            if (U + r < 223) {
                const int base = r * 223 + 8 * k;
                unsigned word = 0;
#pragma unroll
                for (int jj = 0; jj < 8; ++jj) {
                    const int i = 8 * k + jj;
                    unsigned idx = 4u;                       // identity pad
                    if (i < 223) {
                        int2 d = Dbase[base + jj];
                        unsigned px = (unsigned)d.x, py = (unsigned)d.y;
                        if (U + r == 0) px = min(px, 1u);    // y=223 row clamp
                        if (i == 0) py = min(py, 1u);        // x=223 col clamp
                        idx = px * 3u + py;
                    }
                    word |= idx << (4 * jj);
                }
                pk[r * 29 + k] = word;
            }
        }
    }
    __syncthreads();

    // ---- Phase 1: serial register-window build (lane tid builds row u) ----
    if (tid < 32 && u < 223) {
        const int y = 223 - u;
        const int b0r = (y - 1) * 224, b1r = y * 224, b2r = (y + 1) * 224;
        unsigned short* Lf = &smA[tid * 676];    // row-major [3][224] (+4 pad)
        const unsigned* pkr = &pk[tid * 29];

        unsigned w00 = b0r + 222, w01 = b0r + 223, w02 = b0r + 224;
        unsigned w10 = b1r + 222, w11 = b1r + 223, w12 = b1r + 224;
        unsigned w20 = b2r + 222, w21 = b2r + 223, w22 = b2r + 224;

        unsigned wA_ = pkr[0], wB_ = pkr[1], wC_ = pkr[2];

#define GB_STEP(KK, CA, CB, CC) {                                               \
            const int x_ = 223 - (ibase + (KK));                                \
            const unsigned wsel_ = (((KK) >> 3) == 0) ? wA_                     \
                                 : ((((KK) >> 3) == 1) ? wB_ : wC_);            \
            const unsigned idx_ = (wsel_ >> (4 * ((KK) & 7))) & 15u;            \
            unsigned v_ = w0##CA;                                               \
            v_ = idx_ == 1 ? w0##CB : v_;  v_ = idx_ == 2 ? w0##CC : v_;        \
            v_ = idx_ == 3 ? w1##CA : v_;  v_ = idx_ == 4 ? w1##CB : v_;        \
            v_ = idx_ == 5 ? w1##CC : v_;  v_ = idx_ == 6 ? w2##CA : v_;        \
            v_ = idx_ == 7 ? w2##CB : v_;  v_ = idx_ == 8 ? w2##CC : v_;        \
            const unsigned c_ = w1##CB;                                         \
            w0##CA = idx_ == 0 ? c_ : w0##CA;                                   \
            w0##CB = idx_ == 1 ? c_ : w0##CB;                                   \
            w0##CC = idx_ == 2 ? c_ : w0##CC;                                   \
            w1##CA = idx_ == 3 ? c_ : w1##CA;                                   \
            w1##CC = idx_ == 5 ? c_ : w1##CC;                                   \
            w2##CA = idx_ == 6 ? c_ : w2##CA;                                   \
            w2##CB = idx_ == 7 ? c_ : w2##CB;                                   \
            w2##CC = idx_ == 8 ? c_ : w2##CC;                                   \
            w1##CB = v_;                                                        \
            Lf[x_ + 1]   = (unsigned short)w0##CC;                              \
            Lf[x_ + 225] = (unsigned short)w1##CC;                              \
            Lf[x_ + 449] = (unsigned short)w2##CC;                              \
            w0##CC = (unsigned)(b0r + (x_ - 2));                                \
            w1##CC = (unsigned)(b1r + (x_ - 2));                                \
            w2##CC = (unsigned)(b2r + (x_ - 2));                                \
        }
#define GB_TRIPLE(K0) GB_STEP((K0), 0, 1, 2) GB_STEP((K0)+1, 2, 0, 1) GB_STEP((K0)+2, 1, 2, 0)
        // i=0 emission targets (Lf[224],Lf[448],Lf[672]) are junk but are
        // overwritten by the final col-0/col-1 emits below (and 672 is pad).
        for (int blk = 0; blk < 9; ++blk) {           // i = 0..215
            const int ibase = 24 * blk;
            const unsigned nA_ = pkr[min(3 * blk + 3, 27)];
            const unsigned nB_ = pkr[min(3 * blk + 4, 27)];
            const unsigned nC_ = pkr[min(3 * blk + 5, 27)];
            GB_TRIPLE(0)  GB_TRIPLE(3)  GB_TRIPLE(6)  GB_TRIPLE(9)
            GB_TRIPLE(12) GB_TRIPLE(15) GB_TRIPLE(18) GB_TRIPLE(21)
            wA_ = nA_; wB_ = nB_; wC_ = nC_;
        }
        {                                             // i = 216..222
            const int ibase = 216;
            GB_TRIPLE(0) GB_TRIPLE(3) GB_STEP(6, 0, 1, 2)
        }
        Lf[1] = (unsigned short)w01; Lf[225] = (unsigned short)w11; Lf[449] = (unsigned short)w21;
        Lf[0] = (unsigned short)w00; Lf[224] = (unsigned short)w10; Lf[448] = (unsigned short)w20;
#undef GB_TRIPLE
#undef GB_STEP
    }
    __syncthreads();

    // ---- binary tree: 2-hop branch-free levels ----
    level_ds<16, 1,  676,  2,  900>(smA, smB, U, uEnd, tid);  __syncthreads();
    level_ds< 8, 2,  900,  3, 1348>(smB, smA, U, uEnd, tid);  __syncthreads();
    level_ds< 4, 4, 1348,  5, 2244>(smA, smB, U, uEnd, tid);  __syncthreads();
    level_ds< 2, 8, 2244,  9, 4036>(smB, smA, U, uEnd, tid);  __syncthreads();
    level_ds< 1,16, 4036, 17, SLOT32>(smA, outB + (size_t)b * IMG_STRIDE + (size_t)j * SLOT32,
                                      U, uEnd, tid);
}

// ---------------- compose_root: 7 span-32 nodes -> root P (7 clamped hops) ------------
__global__ __launch_bounds__(256) void compose_root_kernel(const unsigned short* __restrict__ in,
                                                           unsigned short* __restrict__ out) {
    const int b = blockIdx.x, sp = blockIdx.y;
    __shared__ unsigned short nd[7 * SLOT32];     // 106624 B
    const unsigned short* base = in + (size_t)b * IMG_STRIDE;
    for (int l = threadIdx.x; l < (7 * SLOT32) / 8; l += 256)
        ((uint4*)nd)[l] = ((const uint4*)base)[l];
    __syncthreads();
    int ys[7], nr[7];
#pragma unroll
    for (int m = 0; m < 7; ++m) node_meta(32 * m, min(32, 223 - 32 * m), ys[m], nr[m]);
    unsigned short* R = out + (size_t)b * IMG_STRIDE;
    const int e0 = sp * 12544;
    for (int e = e0 + threadIdx.x; e < e0 + 12544; e += 256) {
        unsigned q = (unsigned)e;
#pragma unroll
        for (int m = 6; m >= 0; --m) {
            const unsigned qr = q / 224u;
            const int qc = (int)(q - qr * 224u);
            const int off = (int)qr - ys[m];
            const int offc = min(max(off, 0), 33);
            const unsigned r = nd[m * SLOT32 + offc * 224 + qc];
            q = ((unsigned)off < (unsigned)nr[m]) ? r : q;
        }
        R[e] = (unsigned short)q;
    }
}

// ---------------- apply: plane(p) <- plane(P(p)), in-place via LDS ----------------
__global__ __launch_bounds__(256) void apply_kernel(unsigned char* __restrict__ img,
                                                    const unsigned short* __restrict__ P) {
    const int plane = blockIdx.x;
    const int b = plane / 3;
    __shared__ __align__(16) unsigned char im[HH * WW];
    unsigned char* g = img + (size_t)plane * (HH * WW);
    for (int l = threadIdx.x; l < (HH * WW) / 16; l += 256)
        ((int4*)im)[l] = ((const int4*)g)[l];
    __syncthreads();
    const unsigned short* Pp = P + (size_t)b * IMG_STRIDE;
    for (int t = threadIdx.x; t < (HH * WW) / 8; t += 256) {
        uint4 pe = ((const uint4*)Pp)[t];
        unsigned e0 = pe.x & 0xffffu, e1 = pe.x >> 16;
        unsigned e2 = pe.y & 0xffffu, e3 = pe.y >> 16;
        unsigned e4 = pe.z & 0xffffu, e5 = pe.z >> 16;
        unsigned e6 = pe.w & 0xffffu, e7 = pe.w >> 16;
        unsigned lo = (unsigned)im[e0] | ((unsigned)im[e1] << 8)
                    | ((unsigned)im[e2] << 16) | ((unsigned)im[e3] << 24);
        unsigned hi = (unsigned)im[e4] | ((unsigned)im[e5] << 8)
                    | ((unsigned)im[e6] << 16) | ((unsigned)im[e7] << 24);
        ((uint2*)g)[t] = make_uint2(lo, hi);
    }
}

// ---------------- blur2: u8 plane -> blur -> floor/clip -> f32 /255 ----------------
__global__ __launch_bounds__(256) void blur2_kernel(const unsigned char* __restrict__ img,
                                                    float* __restrict__ out) {
    const int rb = blockIdx.x, c = blockIdx.y, b = blockIdx.z;
    const int y0 = rb * 8;
    __shared__ float A[12][WW];
    __shared__ float Bv[8][WW];
    const unsigned char* ip = img + ((size_t)(b * 3 + c)) * HH * WW;

    for (int l = threadIdx.x; l < 12 * WW; l += 256) {
        int r = l / WW, xx = l - r * WW;
        int gy = min(max(y0 + r - 2, 0), HH - 1);
        A[r][xx] = (float)ip[gy * WW + xx];
    }
    __syncthreads();
    for (int l = threadIdx.x; l < 8 * WW; l += 256) {
        int r = l / WW, xx = l - r * WW;
        Bv[r][xx] = KW2 * A[r][xx] + KW1 * A[r + 1][xx] + KW0 * A[r + 2][xx]
                  + KW1 * A[r + 3][xx] + KW2 * A[r + 4][xx];
    }
    __syncthreads();
    float* op = out + ((size_t)(b * 3 + c)) * HH * WW;
    for (int l = threadIdx.x; l < 8 * WW; l += 256) {
        int r = l / WW, xx = l - r * WW;
        int c0 = max(xx - 2, 0), c1 = max(xx - 1, 0);
        int c3 = min(xx + 1, WW - 1), c4 = min(xx + 2, WW - 1);
        float s = KW2 * Bv[r][c0] + KW1 * Bv[r][c1] + KW0 * Bv[r][xx]
                + KW1 * Bv[r][c3] + KW2 * Bv[r][c4];
        s = fminf(fmaxf(s, 0.0f), 255.0f);
        op[(y0 + r) * WW + xx] = floorf(s) / 255.0f;
    }
}

extern "C" void kernel_launch(void* const* d_in, const int* in_sizes, int n_in,
                              void* d_out, int out_size, void* d_ws, size_t ws_size,
                              hipStream_t stream) {
    const float* x      = (const float*)d_in[0];
    const int*   deltas = (const int*)d_in[1];
    float*       out    = (float*)d_out;
    unsigned char* img  = (unsigned char*)d_ws;                 // 9,633,792 B

    unsigned short* bufA = (unsigned short*)d_out;              // 8.03 MB
    unsigned short* bufB = bufA + (size_t)64 * IMG_STRIDE;      // 8.03 MB

    dim3 gb(28, 3, 64);
    blur1_kernel<<<gb, 256, 0, stream>>>(x, img);

    leaf32_kernel<<<dim3(7, 64), 256, 0, stream>>>(deltas, bufB);     // span-32 -> bufB
    compose_root_kernel<<<dim3(64, 4), 256, 0, stream>>>(bufB, bufA); // root P -> bufA

    apply_kernel<<<dim3(192), 256, 0, stream>>>(img, bufA);
    blur2_kernel<<<gb, 256, 0, stream>>>(img, out);
}